// Round 1
// baseline (122.456 us; speedup 1.0000x reference)
//
#include <hip/hip_runtime.h>

#define NA      286   // atoms
#define CIN     23
#define NKH     100   // radial hidden width
#define NKP     50    // k-pairs
#define BATCH   32
#define NB_PAD  320
#define TB      64
#define ATILE   12    // a's per block (3 per wave, 4 waves)
#define APW     3
#define NTILE_A 24
#define NTILE_B 5
#define KQ_N    5     // prep kp-groups
#define KQ_SZ   10    // kp per prep block

#define Y0F      0.28209479177387814f   // 1/(2 sqrt(pi))
#define RSQRT_N  0.05913123960994873f   // 1/sqrt(286)

typedef _Float16 h2v __attribute__((ext_vector_type(2)));
union F4H { float4 f; h2v h[4]; };

__device__ __forceinline__ h2v h2_splat(float x) {
    _Float16 v = (_Float16)x;
    h2v r; r.x = v; r.y = v; return r;
}
__device__ __forceinline__ h2v h2_pack(float a, float b) {
    h2v r; r.x = (_Float16)a; r.y = (_Float16)b; return r;
}
__device__ __forceinline__ h2v h2_fma(h2v a, h2v b, h2v c) {
#if __has_builtin(__builtin_elementwise_fma)
    return __builtin_elementwise_fma(a, b, c);
#else
    return a * b + c;
#endif
}
__device__ __forceinline__ h2v h2_max0(h2v a) {
    h2v z; z.x = (_Float16)0.f; z.y = (_Float16)0.f;
#if __has_builtin(__builtin_elementwise_max)
    return __builtin_elementwise_max(a, z);
#else
    h2v r; r.x = a.x > z.x ? a.x : z.x; r.y = a.y > z.y ? a.y : z.y; return r;
#endif
}
__device__ __forceinline__ float fdot2f(h2v a, h2v b, float c) {
#if __has_builtin(__builtin_amdgcn_fdot2)
    return __builtin_amdgcn_fdot2(a, b, c, false);
#else
    return c + (float)a.x * (float)b.x + (float)a.y * (float)b.y;
#endif
}

// cos((pi/2)*x) for |x| <= 1; |err| <= ~3e-5
__device__ __forceinline__ float cos_half_pi(float x) {
    float t = 1.5707963267948966f * x;
    float w = t * t;
    return 1.f + w * (-0.5f + w * (4.16666667e-2f + w * (-1.38888889e-3f
               + w * 2.48015873e-5f)));
}

// ---------------------------------------------------------------------------
// Kernel 1: cbuf2[z][kp][b] = h2( Y0*dot(rW2[2kp],f[z,b]), Y0*dot(rW2[2kp+1],f[z,b]) )
// grid (5 bT, 32 z, 5 kQ); 256 thr; each block: 64 b x 10 kp.
// r10: each thread's b (= tid&63) is constant across its kpl iterations ->
// snapshot fb row into 23 VGPRs once; rW2 rows read with wave-uniform index
// directly from global (scalar loads via K$, off the LDS pipe). wlds removed.
// kQ==0 blocks additionally reduce their f-tile to colsum[z][bT][23].
// ---------------------------------------------------------------------------
__global__ void __launch_bounds__(256) prep_kernel(
    const float* __restrict__ feat,   // [B][286][23]
    const float* __restrict__ rW2,    // [100][23]
    const float* __restrict__ rW1,    // [3][100]
    const float* __restrict__ rb1,    // [100]
    h2v* __restrict__ cbuf2,          // [B][50][320]
    float4* __restrict__ wpk,         // [50]
    float* __restrict__ colsum)       // [B][5][23]
{
    __shared__ float flds[TB * CIN];          // 5888 B
    __shared__ float csum[8][CIN];            // 736 B
    const int tid = threadIdx.x;
    const int bT  = blockIdx.x;
    const int z   = blockIdx.y;
    const int kQ  = blockIdx.z;

    if (bT == 0 && z == 0 && kQ == 0 && tid < NKP) {
        int k0 = 2 * tid, k1 = k0 + 1;
        F4H u;
        u.h[0] = h2_pack(rW1[k0],           rW1[k1]);
        u.h[1] = h2_pack(rW1[NKH + k0],     rW1[NKH + k1]);
        u.h[2] = h2_pack(rW1[2 * NKH + k0], rW1[2 * NKH + k1]);
        u.h[3] = h2_pack(rb1[k0],           rb1[k1]);
        wpk[tid] = u.f;
    }

    const int b0 = bT * TB;
    const int nf = ((NA - b0 < TB) ? (NA - b0) : TB) * CIN;
    const float* fsrc = feat + ((size_t)z * NA + b0) * CIN;     // contiguous
    for (int i = tid; i < TB * CIN; i += 256)
        flds[i] = (i < nf) ? fsrc[i] : 0.f;
    __syncthreads();

    // register-cache this thread's b-row (b fixed across its kpl iterations)
    const int b = tid & 63;
    float fb[CIN];
    {
        const float* fbp = &flds[b * CIN];
#pragma unroll
        for (int j = 0; j < CIN; ++j) fb[j] = fbp[j];
    }

    if (kQ == 0) {          // uniform branch (blockIdx.z) — barriers safe
        if (tid < 8 * CIN) {
            int j = tid % CIN, ch = tid / CIN;
            float s = 0.f;
#pragma unroll
            for (int bb = 0; bb < 8; ++bb) s += flds[(ch * 8 + bb) * CIN + j];
            csum[ch][j] = s;
        }
        __syncthreads();
        if (tid < CIN) {
            float s = 0.f;
#pragma unroll
            for (int ch = 0; ch < 8; ++ch) s += csum[ch][tid];
            colsum[((size_t)z * NTILE_B + bT) * CIN + tid] = s;
        }
    }

    // kpl = tid>>6 + {0,4,8} — wave-uniform each iteration -> rW2 row goes
    // through the scalar path (s_load, K$-resident 9.2 KB table).
    for (int kpl = (tid >> 6); kpl < KQ_SZ; kpl += 4) {
        const int kp = kQ * KQ_SZ + kpl;
        const float* w = rW2 + (size_t)kp * 2 * CIN;   // wave-uniform address
        float s0 = 0.f, s1 = 0.f;
#pragma unroll
        for (int j = 0; j < CIN; ++j) {
            s0 = fmaf(fb[j], w[j], s0);
            s1 = fmaf(fb[j], w[CIN + j], s1);
        }
        cbuf2[((size_t)z * NKP + kp) * NB_PAD + b0 + b] = h2_pack(s0 * Y0F, s1 * Y0F);
    }
}

// ---------------------------------------------------------------------------
// Kernel 2: partial[bT][z][a] = sum_{b in tile} sum_kp dot2(relu(u@W), c)
// grid (24 aT, 32 z, 5 bT) = 3840 blocks. 256 thr.
// r10: LDS-pipe offload. The old loop issued 1 uniform ds_read_b128 +
// 1 ds_read_b32 per kp (CU-level bottleneck: 1 LDS pipe / 32 waves vs
// 4 SIMDs). Now: w comes from wpk[] with a wave-uniform index -> scalar
// s_load_dwordx4 (K$, 800 B table); c comes straight from global cbuf2
// (coalesced 256 B/wave b32, L1/L2-resident 2 MB) on the idle VMEM pipe.
// No c-tile staging, no staging barrier; LDS holds only ga (144 B).
// Inner loop becomes pure VALU-bound: 15 pk-f16 ops per kp.
// ---------------------------------------------------------------------------
__global__ void __launch_bounds__(256, 8) pair_kernel(
    const float* __restrict__ geom,      // [B][286][3]
    const h2v* __restrict__ cbuf2,       // [B][50][320]
    const float4* __restrict__ wpk,      // [50]
    float* __restrict__ feats_part)      // [5][B][288]
{
    __shared__ float ga[ATILE * 3];

    const int tid   = threadIdx.x;
    const int z     = blockIdx.y;
    const int bT    = blockIdx.z;
    const int aBase = blockIdx.x * ATILE;

    if (tid < ATILE * 3) {
        int aa = aBase + tid / 3;
        int d  = tid - 3 * (tid / 3);
        ga[tid] = (aa < NA) ? geom[((size_t)z * NA + aa) * 3 + d] : 0.f;
    }
    __syncthreads();

    const int wave = tid >> 6;
    const int lane = tid & 63;

    const int b = bT * TB + lane;
    float gbx = 0.f, gby = 0.f, gbz = 0.f;
    if (b < NA) {
        const float* g = geom + ((size_t)z * NA + b) * 3;
        gbx = g[0]; gby = g[1]; gbz = g[2];
    }

    // basis, once per (a, b) pair
    h2v u0[APW], u1[APW], u2[APW];
#pragma unroll
    for (int i = 0; i < APW; ++i) {
        float axv = ga[(wave * APW + i) * 3 + 0];
        float ayv = ga[(wave * APW + i) * 3 + 1];
        float azv = ga[(wave * APW + i) * 3 + 2];
        float dx = gbx - axv, dy = gby - ayv, dz = gbz - azv;
        float r  = sqrtf(fmaf(dx, dx, fmaf(dy, dy, fmaf(dz, dz, 1e-12f))));
        float zz = r * (1.f / 1.5f);            // >= 0
        u0[i] = h2_splat(cos_half_pi(fminf(zz, 1.f)));
        u1[i] = h2_splat(cos_half_pi(fminf(fmaxf(zz - 1.f, -1.f), 1.f)));
        u2[i] = h2_splat(cos_half_pi(fminf(fmaxf(zz - 2.f, -1.f), 1.f)));
    }

    float acc[APW] = {0.f, 0.f, 0.f};
    const h2v* cg = cbuf2 + (size_t)z * NKP * NB_PAD + bT * TB + lane;

#pragma unroll 10
    for (int kp = 0; kp < NKP; ++kp) {
        F4H u; u.f = wpk[kp];                // wave-uniform -> s_load_dwordx4
        h2v cb = cg[(size_t)kp * NB_PAD];    // coalesced global b32, L1-hot
#pragma unroll
        for (int i = 0; i < APW; ++i) {
            h2v s = h2_fma(u0[i], u.h[0],
                    h2_fma(u1[i], u.h[1],
                    h2_fma(u2[i], u.h[2], u.h[3])));
            acc[i] = fdot2f(h2_max0(s), cb, acc[i]);
        }
    }

#pragma unroll
    for (int i = 0; i < APW; ++i) {
        float v = acc[i];
        for (int off = 32; off; off >>= 1) v += __shfl_xor(v, off);
        if (lane == 0) {
            int a = aBase + wave * APW + i;
            if (a < NA)
                feats_part[((size_t)bT * BATCH + z) * 288 + a] = v * RSQRT_N;
        }
    }
}

// ---------------------------------------------------------------------------
// Kernel 3: head, 256 thr per z. Sums 5 b-tile partials; cz from precomputed
// colsum (115 contiguous floats) instead of a strided featIn pass:
//   h1[j] = relu( sum_a fs[a]*W[a,j] + cz * sum_a W[a,j] + b[j] )
// ---------------------------------------------------------------------------
__global__ void __launch_bounds__(256) head_kernel(
    const float* __restrict__ featsP,   // [5][B][288]
    const float* __restrict__ colsum,   // [B][5][23]
    const float* __restrict__ rb2,      // [23]
    const float* __restrict__ fc1W, const float* __restrict__ fc1b,
    const float* __restrict__ fc2W, const float* __restrict__ fc2b,
    const float* __restrict__ fc3W, const float* __restrict__ fc3b,
    float* __restrict__ out)            // [B]
{
    __shared__ float fsum[NA];
    __shared__ float ps0[CIN];
    __shared__ float po[8][30], pw[8][30];
    __shared__ float czs;
    __shared__ float h1[30], hh2[10];

    const int z = blockIdx.x, tid = threadIdx.x;

    for (int a = tid; a < NA; a += 256) {
        float s = 0.f;
#pragma unroll
        for (int bt = 0; bt < NTILE_B; ++bt)
            s += featsP[((size_t)bt * BATCH + z) * 288 + a];
        fsum[a] = s;
    }

    if (tid < CIN) {
        float s = 0.f;
#pragma unroll
        for (int bt = 0; bt < NTILE_B; ++bt)
            s += colsum[((size_t)z * NTILE_B + bt) * CIN + tid];
        ps0[tid] = s * rb2[tid];
    }
    __syncthreads();
    if (tid == 0) {
        float s = 0.f;
#pragma unroll
        for (int j = 0; j < CIN; ++j) s += ps0[j];
        czs = s * (Y0F * RSQRT_N);
    }

    // fc1 partials: 8 a-chunks x 30 outputs
    if (tid < 240) {
        int j = tid % 30, ch = tid / 30;
        int a0 = ch * 36, a1 = (a0 + 36 < NA) ? a0 + 36 : NA;
        float o = 0.f, ws = 0.f;
#pragma unroll 4
        for (int a = a0; a < a1; ++a) {
            float w = fc1W[a * 30 + j];
            o  = fmaf(fsum[a], w, o);
            ws += w;
        }
        po[ch][j] = o; pw[ch][j] = ws;
    }
    __syncthreads();
    if (tid < 30) {
        float o = 0.f, ws = 0.f;
#pragma unroll
        for (int ch = 0; ch < 8; ++ch) { o += po[ch][tid]; ws += pw[ch][tid]; }
        h1[tid] = fmaxf(o + czs * ws + fc1b[tid], 0.f);
    }
    __syncthreads();
    if (tid < 10) {
        float v = fc2b[tid];
#pragma unroll
        for (int t = 0; t < 30; ++t) v = fmaf(h1[t], fc2W[t * 10 + tid], v);
        hh2[tid] = fmaxf(v, 0.f);
    }
    __syncthreads();
    if (tid == 0) {
        float v = fc3b[0];
#pragma unroll
        for (int t = 0; t < 10; ++t) v = fmaf(hh2[t], fc3W[t], v);
        out[z] = v;
    }
}

// ---------------------------------------------------------------------------
extern "C" void kernel_launch(void* const* d_in, const int* in_sizes, int n_in,
                              void* d_out, int out_size, void* d_ws, size_t ws_size,
                              hipStream_t stream) {
    const float* features = (const float*)d_in[1];
    const float* geometry = (const float*)d_in[2];
    const float* rW1  = (const float*)d_in[3];
    const float* rb1  = (const float*)d_in[4];
    const float* rW2  = (const float*)d_in[5];
    const float* rb2  = (const float*)d_in[6];
    const float* fc1W = (const float*)d_in[7];
    const float* fc1b = (const float*)d_in[8];
    const float* fc2W = (const float*)d_in[9];
    const float* fc2b = (const float*)d_in[10];
    const float* fc3W = (const float*)d_in[11];
    const float* fc3b = (const float*)d_in[12];

    char* ws = (char*)d_ws;
    float4* wpk    = (float4*)ws;                                    // 800 B
    h2v*    cbuf2  = (h2v*)(ws + 1024);                              // 2.048 MB
    float*  featsP = (float*)(ws + 1024 + (size_t)BATCH * NKP * NB_PAD * 4);
    float*  colsum = featsP + (size_t)NTILE_B * BATCH * 288;         // 32*5*23 f32

    float* out = (float*)d_out;

    prep_kernel<<<dim3(NTILE_B, BATCH, KQ_N), 256, 0, stream>>>(
        features, rW2, rW1, rb1, cbuf2, wpk, colsum);
    pair_kernel<<<dim3(NTILE_A, BATCH, NTILE_B), 256, 0, stream>>>(
        geometry, cbuf2, wpk, featsP);
    head_kernel<<<BATCH, 256, 0, stream>>>(
        featsP, colsum, rb2, fc1W, fc1b, fc2W, fc2b, fc3W, fc3b, out);
}